// Round 1
// baseline (62.866 us; speedup 1.0000x reference)
//
#include <hip/hip_runtime.h>

// LinearAutoDecoder: rgb[n, j] = dot(X[n, 0:63],  W_pos[3*cid[n]+j, :]) +
//                                dot(X[n, 63:127], W_feat[3*cid[n]+j, :])
// One wave (64 lanes) per point. Lane i covers feature k=i and k=64+i of the
// concatenated 127-wide row. Coalesced X reads; W rows are wave-uniform
// (same cluster id for all lanes) and L2-hot. Butterfly shuffle reduction.

constexpr int ROWW = 127;   // 63 pos + 64 latent

__global__ __launch_bounds__(256, 8) void lad_kernel(
    const float* __restrict__ X,
    const int*   __restrict__ cid,
    const float* __restrict__ Wp,   // [768][63]
    const float* __restrict__ Wf,   // [768][64]
    float*       __restrict__ out,  // [N][3]
    int npts)
{
    const int lane = threadIdx.x & 63;
    const int wid  = (blockIdx.x * blockDim.x + threadIdx.x) >> 6;
    const int nW   = (gridDim.x * blockDim.x) >> 6;
    const bool lo  = (lane < 63);

    // Feature mapping for lane i:
    //   k = i      : i<63 -> W_pos[r][i]        ; i==63 -> W_feat[r][0]
    //   k = 64+i   : i<63 -> W_feat[r][i+1]     ; i==63 -> (none, zero)
    for (int n = wid; n < npts; n += 2 * nW) {
        const int n2 = n + nW;
        const bool has2 = (n2 < npts);

        // ---- issue both points' X / cid loads up front (MLP) ----
        const float* x0 = X + (size_t)n * ROWW;
        const float xa0 = x0[lane];
        const float xb0 = lo ? x0[64 + lane] : 0.0f;
        const int   c0  = cid[n];

        float xa1 = 0.0f, xb1 = 0.0f;
        int   c1  = 0;
        if (has2) {
            const float* x1 = X + (size_t)n2 * ROWW;
            xa1 = x1[lane];
            xb1 = lo ? x1[64 + lane] : 0.0f;
            c1  = cid[n2];
        }

        // ---- weight loads + per-lane partials ----
        float acc0[3], acc1[3];
        #pragma unroll
        for (int j = 0; j < 3; ++j) {
            const int r = 3 * c0 + j;
            const float* pa = lo ? (Wp + (size_t)r * 63 + lane)
                                 : (Wf + (size_t)r * 64);
            const float wa = *pa;
            const float wb = lo ? Wf[(size_t)r * 64 + lane + 1] : 0.0f;
            acc0[j] = fmaf(xa0, wa, xb0 * wb);
        }
        #pragma unroll
        for (int j = 0; j < 3; ++j) {
            const int r = 3 * c1 + j;
            const float* pa = lo ? (Wp + (size_t)r * 63 + lane)
                                 : (Wf + (size_t)r * 64);
            const float wa = *pa;
            const float wb = lo ? Wf[(size_t)r * 64 + lane + 1] : 0.0f;
            acc1[j] = fmaf(xa1, wa, xb1 * wb);
        }

        // ---- butterfly reductions (interleaved for ILP) ----
        #pragma unroll
        for (int m = 32; m >= 1; m >>= 1) {
            acc0[0] += __shfl_xor(acc0[0], m, 64);
            acc0[1] += __shfl_xor(acc0[1], m, 64);
            acc0[2] += __shfl_xor(acc0[2], m, 64);
            acc1[0] += __shfl_xor(acc1[0], m, 64);
            acc1[1] += __shfl_xor(acc1[1], m, 64);
            acc1[2] += __shfl_xor(acc1[2], m, 64);
        }

        if (lane < 3) {
            const float v0 = (lane == 0) ? acc0[0] : (lane == 1) ? acc0[1] : acc0[2];
            out[3 * (size_t)n + lane] = v0;
        }
        if (has2 && lane < 3) {
            const float v1 = (lane == 0) ? acc1[0] : (lane == 1) ? acc1[1] : acc1[2];
            out[3 * (size_t)n2 + lane] = v1;
        }
    }
}

extern "C" void kernel_launch(void* const* d_in, const int* in_sizes, int n_in,
                              void* d_out, int out_size, void* d_ws, size_t ws_size,
                              hipStream_t stream) {
    const float* X   = (const float*)d_in[0];
    const int*   cid = (const int*)d_in[1];
    const float* Wp  = (const float*)d_in[2];
    const float* Wf  = (const float*)d_in[3];
    float* out = (float*)d_out;
    const int npts = in_sizes[1];   // cluster_ids element count == N

    dim3 grid(2048), block(256);
    hipLaunchKernelGGL(lad_kernel, grid, block, 0, stream,
                       X, cid, Wp, Wf, out, npts);
}

// Round 3
// 39.609 us; speedup vs baseline: 1.5871x; 1.5871x over previous
//
#include <hip/hip_runtime.h>

// LinearAutoDecoder: rgb[n, j] = dot(X[n, 0:63],  W_pos[3*cid[n]+j, :]) +
//                                dot(X[n, 63:127], W_feat[3*cid[n]+j, :])
//
// One wave (64 lanes) per point, 2 points in flight per iteration.
// Lane i covers pos-feature i (i<63, via clamped index + xa zeroed on lane 63)
// and latent-feature i (all 64 lanes). Weight addressing is scalarized via
// readfirstlane(cid) -> SGPR base + VGPR lane offset. Reduction is pure-VALU
// DPP (no DS pipe): quad_perm xor1/xor2, row_shr:4/8, row_bcast:15/31,
// result in lane 63.

constexpr int ROWW = 127;   // 63 pos + 64 latent

template <int CTRL, int RMASK, int BMASK>
__device__ __forceinline__ float dpp_add(float x) {
    int t = __builtin_amdgcn_update_dpp(0, __builtin_bit_cast(int, x),
                                        CTRL, RMASK, BMASK, false);
    return x + __builtin_bit_cast(float, t);
}

// Full-wave64 sum; valid in lane 63 only. rocPRIM-style DPP ladder.
__device__ __forceinline__ float wave_sum63(float x) {
    x = dpp_add<0xB1,  0xF, 0xF>(x);  // quad_perm [1,0,3,2]  (xor 1)
    x = dpp_add<0x4E,  0xF, 0xF>(x);  // quad_perm [2,3,0,1]  (xor 2)
    x = dpp_add<0x114, 0xF, 0xE>(x);  // row_shr:4
    x = dpp_add<0x118, 0xF, 0xC>(x);  // row_shr:8
    x = dpp_add<0x142, 0xA, 0xF>(x);  // row_bcast:15
    x = dpp_add<0x143, 0xC, 0xF>(x);  // row_bcast:31
    return x;
}

__global__ __launch_bounds__(256, 8) void lad_kernel(
    const float* __restrict__ X,
    const int*   __restrict__ cid,
    const float* __restrict__ Wp,   // [768][63]
    const float* __restrict__ Wf,   // [768][64]
    float*       __restrict__ out,  // [N][3]
    int npts)
{
    const int lane  = threadIdx.x & 63;
    const int wid   = (blockIdx.x * blockDim.x + threadIdx.x) >> 6;
    const int nW    = (gridDim.x * blockDim.x) >> 6;
    const int lanec = (lane < 63) ? lane : 62;   // clamped pos index (avoids OOB)
    const bool l63  = (lane == 63);

    for (int n = wid; n < npts; n += 2 * nW) {
        const int n2 = n + nW;
        const bool has2 = (n2 < npts);

        // ---- X / cid loads for both points, issued up front ----
        const float* x0 = X + (size_t)n * ROWW;
        float xa0 = x0[lane];        // pos feature `lane` (lane 63: dead, zeroed)
        float xb0 = x0[63 + lane];   // latent feature `lane` (all 64 valid)
        int   c0  = __builtin_amdgcn_readfirstlane(cid[n]);

        float xa1 = 0.0f, xb1 = 0.0f;
        int   c1  = 0;
        if (has2) {
            const float* x1 = X + (size_t)n2 * ROWW;
            xa1 = x1[lane];
            xb1 = x1[63 + lane];
            c1  = __builtin_amdgcn_readfirstlane(cid[n2]);
        }
        if (l63) { xa0 = 0.0f; xa1 = 0.0f; }

        // ---- weight loads (SGPR base + lane offset) + per-lane partials ----
        const float* wp0 = Wp + (size_t)(3 * c0) * 63;
        const float* wf0 = Wf + (size_t)(3 * c0) * 64;
        const float* wp1 = Wp + (size_t)(3 * c1) * 63;
        const float* wf1 = Wf + (size_t)(3 * c1) * 64;

        float a00 = fmaf(xa0, wp0[lanec],       xb0 * wf0[lane]);
        float a01 = fmaf(xa0, wp0[63 + lanec],  xb0 * wf0[64 + lane]);
        float a02 = fmaf(xa0, wp0[126 + lanec], xb0 * wf0[128 + lane]);
        float a10 = fmaf(xa1, wp1[lanec],       xb1 * wf1[lane]);
        float a11 = fmaf(xa1, wp1[63 + lanec],  xb1 * wf1[64 + lane]);
        float a12 = fmaf(xa1, wp1[126 + lanec], xb1 * wf1[128 + lane]);

        // ---- 6 independent DPP reduction chains (pure VALU, no DS) ----
        a00 = wave_sum63(a00);
        a01 = wave_sum63(a01);
        a02 = wave_sum63(a02);
        a10 = wave_sum63(a10);
        a11 = wave_sum63(a11);
        a12 = wave_sum63(a12);

        if (l63) {
            float* o0 = out + 3 * (size_t)n;
            o0[0] = a00; o0[1] = a01; o0[2] = a02;
            if (has2) {
                float* o1 = out + 3 * (size_t)n2;
                o1[0] = a10; o1[1] = a11; o1[2] = a12;
            }
        }
    }
}

extern "C" void kernel_launch(void* const* d_in, const int* in_sizes, int n_in,
                              void* d_out, int out_size, void* d_ws, size_t ws_size,
                              hipStream_t stream) {
    const float* X   = (const float*)d_in[0];
    const int*   cid = (const int*)d_in[1];
    const float* Wp  = (const float*)d_in[2];
    const float* Wf  = (const float*)d_in[3];
    float* out = (float*)d_out;
    const int npts = in_sizes[1];   // cluster_ids element count == N

    dim3 grid(2048), block(256);
    hipLaunchKernelGGL(lad_kernel, grid, block, 0, stream,
                       X, cid, Wp, Wf, out, npts);
}